// Round 3
// baseline (695.620 us; speedup 1.0000x reference)
//
#include <hip/hip_runtime.h>

typedef float  f32x4  __attribute__((ext_vector_type(4)));
typedef __bf16 bf16x8 __attribute__((ext_vector_type(8)));

#define LOG2E      1.4426950408889634f
#define TWO_LOG2E  2.8853900817779268f

// LDS-only barrier: drains LDS ops but NOT vmcnt, so producer-wave global
// loads stay in flight across it (the compiler's __syncthreads would force
// s_waitcnt vmcnt(0) and kill the pipeline).
#define BAR_LDS() asm volatile("s_waitcnt lgkmcnt(0)\n\ts_barrier" ::: "memory")

__device__ __forceinline__ float fast_tanh(float x) {
    float e = __builtin_amdgcn_exp2f(x * TWO_LOG2E);
    return 1.0f - 2.0f * __builtin_amdgcn_rcpf(e + 1.0f);
}

// A-tile LDS swizzle (verified R2): conflict-free for MFMA read, staging
// write, and context read patterns.
__device__ __forceinline__ int a_chunk(int m, int k8) {
    return (((m >> 4) * 16 + (k8 >> 2)) << 6) +
           ((((k8 & 3) << 4) | (m & 15)) ^ ((k8 >> 2) & 7) ^ (((k8 & 3) << 1) & 7));
}

__device__ __forceinline__ bf16x8 cvt_chunk(f32x4 f0, f32x4 f1) {
    bf16x8 val;
    val[0]=(__bf16)f0[0]; val[1]=(__bf16)f0[1]; val[2]=(__bf16)f0[2]; val[3]=(__bf16)f0[3];
    val[4]=(__bf16)f1[0]; val[5]=(__bf16)f1[1]; val[6]=(__bf16)f1[2]; val[7]=(__bf16)f1[3];
    return val;
}

// ---------------------------------------------------------------------------
// K1a: W_h -> bf16 B-fragment order (unchanged from R2).
// ---------------------------------------------------------------------------
__global__ void wh_swizzle_kernel(const float* __restrict__ Wh,
                                  __bf16* __restrict__ Wswz) {
    int gid = blockIdx.x * 256 + threadIdx.x;
    int n   = gid >> 6;
    int k8  = gid & 63;
    const float* g = Wh + ((long)n << 9) + (k8 << 3);
    bf16x8 val = cvt_chunk(*(const f32x4*)g, *(const f32x4*)(g + 4));
    int chunk = (((n >> 4) * 16 + (k8 >> 2)) << 6) + (((k8 & 3) << 4) | (n & 15));
    *(bf16x8*)(Wswz + ((long)chunk << 3)) = val;
}

// ---------------------------------------------------------------------------
// K1b: q_proj — one wave per (b,o), coalesced + shuffle reduce (unchanged).
// ---------------------------------------------------------------------------
__global__ void qproj_kernel(const float* __restrict__ query,
                             const float* __restrict__ Wq,
                             float* __restrict__ qp) {
    int pair = (blockIdx.x << 2) + (threadIdx.x >> 6);
    int l    = threadIdx.x & 63;
    int b    = pair >> 9;
    long o   = pair & 511;
    const f32x4* q  = (const f32x4*)(query + (b << 9) + (l << 3));
    const f32x4* wr = (const f32x4*)(Wq + (o << 9) + (l << 3));
    f32x4 a0 = q[0], a1 = q[1], w0 = wr[0], w1 = wr[1];
    float acc = a0[0]*w0[0] + a0[1]*w0[1] + a0[2]*w0[2] + a0[3]*w0[3]
              + a1[0]*w1[0] + a1[1]*w1[1] + a1[2]*w1[2] + a1[3]*w1[3];
    #pragma unroll
    for (int off = 1; off < 64; off <<= 1) acc += __shfl_xor(acc, off, 64);
    if (l == 0) qp[pair] = acc;
}

// ---------------------------------------------------------------------------
// K2: persistent producer-consumer pipeline.
// Grid 256 (1 block/CU), 768 threads: waves 0-7 consumers, 8-11 producers.
// Each block: 8 tiles x 64 rows (512 consecutive rows, one b).
// Double-buffered 64-row bf16 A tile (2 x 64 KB LDS).
// ---------------------------------------------------------------------------
__global__ __launch_bounds__(768, 3) void score_ctx_kernel(
    const float*  __restrict__ enc,
    const __bf16* __restrict__ Wswz,
    const float*  __restrict__ qp,
    const float*  __restrict__ v,
    float* __restrict__ alpha_out,   // (B*S) unnormalized e^score
    float* __restrict__ ctx_acc,     // (B*H) atomic accumulation
    float* __restrict__ denom)       // (B)   atomic accumulation
{
    __shared__ __align__(16) unsigned char ldsA[2][65536];
    __shared__ float score_lds[512];
    __shared__ float escore[64];

    const int  t    = threadIdx.x;
    const bool cons = (t < 512);
    const int  w    = t >> 6;        // consumer wave id (0..7)
    const int  l    = t & 63;
    const int  p    = t - 512;       // producer thread id (0..255)
    const long rowB = (long)blockIdx.x << 9;   // 512 rows per block
    const int  b    = (int)(rowB >> 13);

    // consumer-invariant: qp/v fragments (same b for all 8 tiles)
    float qv[4], vv[4];
    if (cons) {
        #pragma unroll
        for (int nt = 0; nt < 4; ++nt) {
            int n = (w << 6) + (nt << 4) + (l & 15);
            qv[nt] = qp[(b << 9) + n];
            vv[nt] = v[n];
        }
    }

    // ---- prologue: producers stage tile 0 into buf 0 ----
    if (!cons) {
        f32x4 g0[16], g1[16];
        #pragma unroll
        for (int j = 0; j < 16; ++j) {
            int cflat = p + (j << 8);
            int m = cflat >> 6, k8 = cflat & 63;
            const float* g = enc + ((rowB + m) << 9) + (k8 << 3);
            g0[j] = *(const f32x4*)g;
            g1[j] = *(const f32x4*)(g + 4);
        }
        #pragma unroll
        for (int j = 0; j < 16; ++j) {
            int cflat = p + (j << 8);
            int m = cflat >> 6, k8 = cflat & 63;
            *(bf16x8*)(ldsA[0] + (a_chunk(m, k8) << 4)) = cvt_chunk(g0[j], g1[j]);
        }
    }
    BAR_LDS();

    float ca[8];
    #pragma unroll
    for (int j = 0; j < 8; ++j) ca[j] = 0.f;
    float dsum = 0.f;
    const bf16x8* Bg = (const bf16x8*)Wswz;

    for (int i = 0; i < 8; ++i) {
        const int  cur  = i & 1;
        const long row0 = rowB + (i << 6);

        f32x4 pg0[16], pg1[16];
        if (!cons) {
            // -- producer phase 1: issue next tile's loads (registers only) --
            if (i < 7) {
                const float* encN = enc + ((row0 + 64) << 9);
                #pragma unroll
                for (int j = 0; j < 16; ++j) {
                    int cflat = p + (j << 8);
                    int m = cflat >> 6, k8 = cflat & 63;
                    const float* g = encN + ((long)m << 9) + (k8 << 3);
                    pg0[j] = *(const f32x4*)g;
                    pg1[j] = *(const f32x4*)(g + 4);
                }
            }
        } else {
            // -- consumer: MFMA K-loop on ldsA[cur], B from L2 w/ prefetch --
            f32x4 acc[4][4];
            #pragma unroll
            for (int nt = 0; nt < 4; ++nt) {
                f32x4 qvv = {qv[nt], qv[nt], qv[nt], qv[nt]};
                #pragma unroll
                for (int mt = 0; mt < 4; ++mt) acc[nt][mt] = qvv;
            }
            const int bbase = (w << 12) + l;
            const unsigned char* lbase = ldsA[cur];
            bf16x8 bcur[4], bnxt[4];
            #pragma unroll
            for (int nt = 0; nt < 4; ++nt) bcur[nt] = Bg[bbase + (nt << 10)];
            #pragma unroll
            for (int s = 0; s < 16; ++s) {
                if (s < 15) {
                    #pragma unroll
                    for (int nt = 0; nt < 4; ++nt)
                        bnxt[nt] = Bg[bbase + (nt << 10) + ((s + 1) << 6)];
                }
                int lowr = l ^ (s & 7) ^ (((l >> 4) << 1) & 7);
                bf16x8 af[4];
                #pragma unroll
                for (int mt = 0; mt < 4; ++mt)
                    af[mt] = *(const bf16x8*)(lbase + (((((mt << 4) + s) << 6) + lowr) << 4));
                #pragma unroll
                for (int nt = 0; nt < 4; ++nt)
                    #pragma unroll
                    for (int mt = 0; mt < 4; ++mt)
                        acc[nt][mt] = __builtin_amdgcn_mfma_f32_16x16x32_bf16(
                            af[mt], bcur[nt], acc[nt][mt], 0, 0, 0);
                #pragma unroll
                for (int nt = 0; nt < 4; ++nt) bcur[nt] = bnxt[nt];
            }
            // -- epilogue: per-row score partials --
            float srow[16];
            #pragma unroll
            for (int q = 0; q < 16; ++q) srow[q] = 0.f;
            #pragma unroll
            for (int nt = 0; nt < 4; ++nt) {
                float vn = vv[nt];
                #pragma unroll
                for (int mt = 0; mt < 4; ++mt)
                    #pragma unroll
                    for (int r = 0; r < 4; ++r)
                        srow[mt * 4 + r] += vn * fast_tanh(acc[nt][mt][r]);
            }
            #pragma unroll
            for (int q = 0; q < 16; ++q) {
                #pragma unroll
                for (int off = 1; off < 16; off <<= 1)
                    srow[q] += __shfl_xor(srow[q], off, 64);
            }
            if ((l & 15) == 0) {
                int qd = l >> 4;
                #pragma unroll
                for (int mt = 0; mt < 4; ++mt)
                    #pragma unroll
                    for (int r = 0; r < 4; ++r)
                        score_lds[(w << 6) + (mt << 4) + (qd << 2) + r] = srow[mt * 4 + r];
            }
        }
        BAR_LDS();   // A: score_lds visible

        if (cons && t < 64) {
            float sc = 0.f;
            #pragma unroll
            for (int ww = 0; ww < 8; ++ww) sc += score_lds[(ww << 6) + t];
            float e = __builtin_amdgcn_exp2f(sc * LOG2E);
            alpha_out[row0 + t] = e;
            escore[t] = e;
            float ssum = e;
            #pragma unroll
            for (int off = 1; off < 64; off <<= 1) ssum += __shfl_xor(ssum, off, 64);
            dsum += ssum;
        }
        BAR_LDS();   // B: escore visible

        if (cons) {
            // -- context partial from resident tile --
            #pragma unroll
            for (int ii = 0; ii < 8; ++ii) {
                int m = (w << 3) + ii;
                float em = escore[m];
                bf16x8 av = *(const bf16x8*)(ldsA[cur] + (a_chunk(m, l) << 4));
                #pragma unroll
                for (int j = 0; j < 8; ++j) ca[j] += em * (float)av[j];
            }
        } else if (i < 7) {
            // -- producer phase 2: cvt + write next buffer --
            #pragma unroll
            for (int j = 0; j < 16; ++j) {
                int cflat = p + (j << 8);
                int m = cflat >> 6, k8 = cflat & 63;
                *(bf16x8*)(ldsA[1 - cur] + (a_chunk(m, k8) << 4)) = cvt_chunk(pg0[j], pg1[j]);
            }
        }
        BAR_LDS();   // D: buffer handoff
    }

    // ---- block epilogue: ctx transpose + one atomic set ----
    float* part = (float*)ldsA;      // reuse tile memory (stride 9 anti-conflict)
    if (cons) {
        #pragma unroll
        for (int j = 0; j < 8; ++j) part[t * 9 + j] = ca[j];
    }
    BAR_LDS();
    if (cons) {
        int h = t, k8h = h >> 3, j = h & 7;
        float sum = 0.f;
        #pragma unroll
        for (int rg = 0; rg < 8; ++rg) sum += part[((rg << 6) | k8h) * 9 + j];
        atomicAdd(ctx_acc + ((long)b << 9) + h, sum);
        if (t == 0) atomicAdd(denom + b, dsum);
    }
}

// ---------------------------------------------------------------------------
// K3: normalize both outputs by denom[b]
// ---------------------------------------------------------------------------
__global__ void normalize_kernel(const float* __restrict__ ctx_acc,
                                 const float* __restrict__ denom,
                                 float* __restrict__ out) {
    int i = blockIdx.x * 256 + threadIdx.x;
    if (i < 8192) {
        int b = i >> 9;
        out[i] = ctx_acc[i] / denom[b];
    } else if (i < 8192 + 131072) {
        int b = (i - 8192) >> 13;
        out[i] = out[i] / denom[b];
    }
}

extern "C" void kernel_launch(void* const* d_in, const int* in_sizes, int n_in,
                              void* d_out, int out_size, void* d_ws, size_t ws_size,
                              hipStream_t stream) {
    const float* enc   = (const float*)d_in[0];  // (16,8192,512)
    const float* query = (const float*)d_in[1];  // (16,512)
    const float* Wh    = (const float*)d_in[2];  // (512,512)
    const float* Wq    = (const float*)d_in[3];  // (512,512)
    const float* v     = (const float*)d_in[4];  // (512,)
    float* out = (float*)d_out;                  // [context 8192 | alpha 131072]

    char* ws = (char*)d_ws;
    float*  ctx_acc = (float*)ws;                // 8192 floats
    float*  denom   = (float*)(ws + 32768);      // 16 floats
    float*  qp      = (float*)(ws + 32832);      // 8192 floats
    __bf16* Wswz    = (__bf16*)(ws + 65600);     // 262144 bf16, 16B aligned

    hipMemsetAsync(ws, 0, 32832, stream);        // zero ctx_acc + denom
    wh_swizzle_kernel<<<128, 256, 0, stream>>>(Wh, Wswz);
    qproj_kernel<<<2048, 256, 0, stream>>>(query, Wq, qp);
    score_ctx_kernel<<<256, 768, 0, stream>>>(enc, Wswz, qp, v,
                                              out + 8192, ctx_acc, denom);
    normalize_kernel<<<544, 256, 0, stream>>>(ctx_acc, denom, out);
}